// Round 6
// baseline (3154.939 us; speedup 1.0000x reference)
//
#include <hip/hip_runtime.h>
#include <hip/hip_bf16.h>

#define B_ 256
#define T_ 2048
#define I_ 64
#define H_ 128
#define G_ 384
#define O_ 10
#define WS_NEED ((size_t)B_ * (size_t)T_ * (size_t)H_ * 2u)  // h0 seq fp16

typedef _Float16 half2_t __attribute__((ext_vector_type(2)));
typedef _Float16 half8_t __attribute__((ext_vector_type(8)));

// ---- fast activations via exp2; no clamps (inf/0 propagate to exact 0/1/±1) ----
__device__ __forceinline__ float sigm_(float s) {
  float e = __builtin_amdgcn_exp2f(s * -1.44269504f);
  return __builtin_amdgcn_rcpf(1.f + e);
}
__device__ __forceinline__ float tanh_(float s) {
  float e = __builtin_amdgcn_exp2f(s * 2.88539009f);
  return 1.f - 2.f * __builtin_amdgcn_rcpf(1.f + e);
}

// ---- octet (8-lane) sum via DPP: xor1, xor2 (quad_perm), half-mirror (i<->7-i) ----
__device__ __forceinline__ float octsum_(float v) {
  int t;
  t = __builtin_amdgcn_update_dpp(0, __builtin_bit_cast(int, v), 0xB1, 0xF, 0xF, true);
  v += __builtin_bit_cast(float, t);
  t = __builtin_amdgcn_update_dpp(0, __builtin_bit_cast(int, v), 0x4E, 0xF, 0xF, true);
  v += __builtin_bit_cast(float, t);
  t = __builtin_amdgcn_update_dpp(0, __builtin_bit_cast(int, v), 0x141, 0xF, 0xF, true);
  v += __builtin_bit_cast(float, t);
  return v;
}

// 8 fp32 -> named half8 (R1/R2 lesson: named SSA vectors only, never arrays)
#define CVT8(DST, SRC) do { const float* s_ = (SRC); half8_t w_; \
  w_[0]=(_Float16)s_[0]; w_[1]=(_Float16)s_[1]; w_[2]=(_Float16)s_[2]; w_[3]=(_Float16)s_[3]; \
  w_[4]=(_Float16)s_[4]; w_[5]=(_Float16)s_[5]; w_[6]=(_Float16)s_[6]; w_[7]=(_Float16)s_[7]; \
  (DST) = w_; } while(0)

__device__ __forceinline__ float dot8h(half8_t w, half8_t v, float acc) {
  acc = __builtin_amdgcn_fdot2(__builtin_shufflevector(w,w,0,1), __builtin_shufflevector(v,v,0,1), acc, false);
  acc = __builtin_amdgcn_fdot2(__builtin_shufflevector(w,w,2,3), __builtin_shufflevector(v,v,2,3), acc, false);
  acc = __builtin_amdgcn_fdot2(__builtin_shufflevector(w,w,4,5), __builtin_shufflevector(v,v,4,5), acc, false);
  acc = __builtin_amdgcn_fdot2(__builtin_shufflevector(w,w,6,7), __builtin_shufflevector(v,v,6,7), acc, false);
  return acc;
}
__device__ __forceinline__ float dot4f(float4 w, float4 v, float acc) {
  acc = fmaf(w.x, v.x, acc); acc = fmaf(w.y, v.y, acc);
  acc = fmaf(w.z, v.z, acc); acc = fmaf(w.w, v.w, acc);
  return acc;
}

// =====================================================================
// Kernel 1: GRU layer 0.  1024 thr = 128 octets; octet j owns h[j] and
// gates {j, 128+j, 256+j}; lane s covers x[s*8:+8) (f32) and h[s*16:+16).
// x streamed via 4-deep LDS ring (global_load_lds by wave0, 3 ahead,
// counted vmcnt - never 0).  One barrier per phase.  h0 seq -> ws (fp16).
// =====================================================================
__global__ __launch_bounds__(1024, 4)
__attribute__((amdgpu_waves_per_eu(4, 4)))
void gru_l0(const float* __restrict__ x,
            const float* __restrict__ Wih, const float* __restrict__ Whh,
            const float* __restrict__ bih, const float* __restrict__ bhh,
            ushort* __restrict__ wsh)
{
  const int b = blockIdx.x, tid = threadIdx.x;
  const int j = tid >> 3, s = tid & 7;

  __shared__ alignas(16) float  xst[4][I_];   // x(t) ring, f32
  __shared__ alignas(16) ushort h0p[2][H_];   // h fp16, double-buffered

  // ---- resident weights (all named SSA) ----
  float4 wxr_a, wxr_b, wxz_a, wxz_b, wxn_a, wxn_b;        // Wih slices, f32
  half8_t whr_a, whr_b, whz_a, whz_b, whn_a, whn_b;       // Whh slices, f16
  {
    const float* p;
    p = Wih + (size_t)j * I_ + s * 8;            wxr_a = *(const float4*)p; wxr_b = *(const float4*)(p + 4);
    p = Wih + (size_t)(H_ + j) * I_ + s * 8;     wxz_a = *(const float4*)p; wxz_b = *(const float4*)(p + 4);
    p = Wih + (size_t)(2*H_ + j) * I_ + s * 8;   wxn_a = *(const float4*)p; wxn_b = *(const float4*)(p + 4);
    p = Whh + (size_t)j * H_ + s * 16;           CVT8(whr_a, p); CVT8(whr_b, p + 8);
    p = Whh + (size_t)(H_ + j) * H_ + s * 16;    CVT8(whz_a, p); CVT8(whz_b, p + 8);
    p = Whh + (size_t)(2*H_ + j) * H_ + s * 16;  CVT8(whn_a, p); CVT8(whn_b, p + 8);
  }
  const float br  = bih[j] + bhh[j];
  const float bz  = bih[H_ + j] + bhh[H_ + j];
  const float bin = bih[2*H_ + j], bhn = bhh[2*H_ + j];

  const size_t xrow = (size_t)b * T_;
  float hprev = 0.f;

  // ---- prologue: zero h0p[0]; prefetch x(0..2) ----
  if (tid < H_) h0p[0][tid] = 0;
  if (tid < 16) {
    __builtin_amdgcn_global_load_lds(x + (xrow + 0) * I_ + tid * 4, &xst[0][0], 16, 0, 0);
    __builtin_amdgcn_global_load_lds(x + (xrow + 1) * I_ + tid * 4, &xst[1][0], 16, 0, 0);
    __builtin_amdgcn_global_load_lds(x + (xrow + 2) * I_ + tid * 4, &xst[2][0], 16, 0, 0);
  }
  if (tid < 64) { asm volatile("s_waitcnt vmcnt(0)" ::: "memory"); }
  __syncthreads();

  for (int t = 0; t < T_; ++t) {
    // stage x(t+3)
    if (tid < 16) {
      int tt = t + 3; if (tt > T_ - 1) tt = T_ - 1;
      __builtin_amdgcn_global_load_lds(x + (xrow + tt) * I_ + tid * 4,
                                       &xst[(t + 3) & 3][0], 16, 0, 0);
    }
    // dots
    const float4*  xr = (const float4*)&xst[t & 3][s * 8];
    const float4   xa = xr[0], xb = xr[1];
    const half8_t* hr = (const half8_t*)&h0p[t & 1][s * 16];
    const half8_t  ha = hr[0], hb = hr[1];

    float accr = dot4f(wxr_a, xa, dot4f(wxr_b, xb, 0.f));
    float accz = dot4f(wxz_a, xa, dot4f(wxz_b, xb, 0.f));
    float axn  = dot4f(wxn_a, xa, dot4f(wxn_b, xb, 0.f));
    accr = dot8h(whr_a, ha, dot8h(whr_b, hb, accr));
    accz = dot8h(whz_a, ha, dot8h(whz_b, hb, accz));
    float ahn  = dot8h(whn_a, ha, dot8h(whn_b, hb, 0.f));

    const float vr = octsum_(accr), vz = octsum_(accz);
    const float an = octsum_(axn),  hn_ = octsum_(ahn);

    const float r = sigm_(vr + br);
    const float z = sigm_(vz + bz);
    const float n = tanh_(fmaf(r, hn_ + bhn, an + bin));
    const float hnew = fmaf(z, hprev - n, n);
    hprev = hnew;

    if (s == 0) {
      const ushort hbits = __builtin_bit_cast(ushort, (_Float16)hnew);
      h0p[(t + 1) & 1][j] = hbits;
      wsh[(xrow + t) * H_ + j] = hbits;
    }
    // allow 2 newest glls + this phase's store to stay in flight
    if (tid < 64) { asm volatile("s_waitcnt vmcnt(3)" ::: "memory"); }
    __syncthreads();
  }
}

// =====================================================================
// Kernel 2: GRU layer 1 + final FC.  Same octet structure; h0(t) streamed
// from ws through a 4-deep LDS ring; h1 feedback double-buffered in LDS.
// =====================================================================
__global__ __launch_bounds__(1024, 4)
__attribute__((amdgpu_waves_per_eu(4, 4)))
void gru_l1(const ushort* __restrict__ wsh,
            const float* __restrict__ Wih, const float* __restrict__ Whh,
            const float* __restrict__ bih, const float* __restrict__ bhh,
            const float* __restrict__ fcW, const float* __restrict__ fcb,
            float* __restrict__ out)
{
  const int b = blockIdx.x, tid = threadIdx.x;
  const int j = tid >> 3, s = tid & 7;

  __shared__ alignas(16) ushort h0st[4][H_];  // h0(t) ring (from ws)
  __shared__ alignas(16) ushort h1p[2][H_];   // h1 fp16, double-buffered
  __shared__ float hfin[H_];

  half8_t wir_a, wir_b, wiz_a, wiz_b, win_a, win_b;   // Wih1 slices
  half8_t whr_a, whr_b, whz_a, whz_b, whn_a, whn_b;   // Whh1 slices
  {
    const float* p;
    p = Wih + (size_t)j * H_ + s * 16;           CVT8(wir_a, p); CVT8(wir_b, p + 8);
    p = Wih + (size_t)(H_ + j) * H_ + s * 16;    CVT8(wiz_a, p); CVT8(wiz_b, p + 8);
    p = Wih + (size_t)(2*H_ + j) * H_ + s * 16;  CVT8(win_a, p); CVT8(win_b, p + 8);
    p = Whh + (size_t)j * H_ + s * 16;           CVT8(whr_a, p); CVT8(whr_b, p + 8);
    p = Whh + (size_t)(H_ + j) * H_ + s * 16;    CVT8(whz_a, p); CVT8(whz_b, p + 8);
    p = Whh + (size_t)(2*H_ + j) * H_ + s * 16;  CVT8(whn_a, p); CVT8(whn_b, p + 8);
  }
  const float br  = bih[j] + bhh[j];
  const float bz  = bih[H_ + j] + bhh[H_ + j];
  const float bin = bih[2*H_ + j], bhn = bhh[2*H_ + j];

  const size_t hrow = (size_t)b * T_;
  float hprev = 0.f;

  if (tid < H_) h1p[0][tid] = 0;
  if (tid < 16) {
    __builtin_amdgcn_global_load_lds(wsh + (hrow + 0) * H_ + tid * 8, &h0st[0][0], 16, 0, 0);
    __builtin_amdgcn_global_load_lds(wsh + (hrow + 1) * H_ + tid * 8, &h0st[1][0], 16, 0, 0);
    __builtin_amdgcn_global_load_lds(wsh + (hrow + 2) * H_ + tid * 8, &h0st[2][0], 16, 0, 0);
  }
  if (tid < 64) { asm volatile("s_waitcnt vmcnt(0)" ::: "memory"); }
  __syncthreads();

  for (int t = 0; t < T_; ++t) {
    if (tid < 16) {
      int tt = t + 3; if (tt > T_ - 1) tt = T_ - 1;
      __builtin_amdgcn_global_load_lds(wsh + (hrow + tt) * H_ + tid * 8,
                                       &h0st[(t + 3) & 3][0], 16, 0, 0);
    }
    const half8_t* ar = (const half8_t*)&h0st[t & 3][s * 16];
    const half8_t  aa = ar[0], ab = ar[1];
    const half8_t* hr = (const half8_t*)&h1p[t & 1][s * 16];
    const half8_t  ha = hr[0], hb = hr[1];

    float accr = dot8h(wir_a, aa, dot8h(wir_b, ab, 0.f));
    float accz = dot8h(wiz_a, aa, dot8h(wiz_b, ab, 0.f));
    float axn  = dot8h(win_a, aa, dot8h(win_b, ab, 0.f));
    accr = dot8h(whr_a, ha, dot8h(whr_b, hb, accr));
    accz = dot8h(whz_a, ha, dot8h(whz_b, hb, accz));
    float ahn  = dot8h(whn_a, ha, dot8h(whn_b, hb, 0.f));

    const float vr = octsum_(accr), vz = octsum_(accz);
    const float an = octsum_(axn),  hn_ = octsum_(ahn);

    const float r = sigm_(vr + br);
    const float z = sigm_(vz + bz);
    const float n = tanh_(fmaf(r, hn_ + bhn, an + bin));
    const float hnew = fmaf(z, hprev - n, n);
    hprev = hnew;

    if (s == 0) h1p[(t + 1) & 1][j] = __builtin_bit_cast(ushort, (_Float16)hnew);
    if (tid < 64) { asm volatile("s_waitcnt vmcnt(2)" ::: "memory"); }
    __syncthreads();
  }

  if (s == 0) hfin[j] = hprev;
  __syncthreads();
  if (tid < O_) {
    float a = fcb[tid];
    const float* wr = fcW + (size_t)tid * H_;
    for (int k = 0; k < H_; ++k) a = fmaf(wr[k], hfin[k], a);
    out[(size_t)b * O_ + tid] = a;
  }
}

// =====================================================================
// Fallback (R5 kernel, proven correct at 2.56ms): used only if ws_size
// cannot hold the 134MB h0 sequence.
// =====================================================================
#define D8(S0,S1,S2,S3,W,XV) do { half8_t xv_ = (XV); half8_t w_ = (W); \
  S0 = __builtin_amdgcn_fdot2(__builtin_shufflevector(w_,w_,0,1), __builtin_shufflevector(xv_,xv_,0,1), (S0), false); \
  S1 = __builtin_amdgcn_fdot2(__builtin_shufflevector(w_,w_,2,3), __builtin_shufflevector(xv_,xv_,2,3), (S1), false); \
  S2 = __builtin_amdgcn_fdot2(__builtin_shufflevector(w_,w_,4,5), __builtin_shufflevector(xv_,xv_,4,5), (S2), false); \
  S3 = __builtin_amdgcn_fdot2(__builtin_shufflevector(w_,w_,6,7), __builtin_shufflevector(xv_,xv_,6,7), (S3), false); \
} while(0)

__device__ __forceinline__ float sigm2_(float s) {
  s = fminf(fmaxf(s, -30.f), 30.f);
  return __builtin_amdgcn_rcpf(1.f + __expf(-s));
}
__device__ __forceinline__ float tanh2_(float s) {
  s = fminf(fmaxf(s, -15.f), 15.f);
  return 1.f - 2.f * __builtin_amdgcn_rcpf(1.f + __expf(2.f * s));
}

__global__ __launch_bounds__(768, 3) void gru_net(
    const float* __restrict__ x,
    const float* __restrict__ Wih0, const float* __restrict__ Whh0,
    const float* __restrict__ bih0, const float* __restrict__ bhh0,
    const float* __restrict__ Wih1, const float* __restrict__ Whh1,
    const float* __restrict__ bih1, const float* __restrict__ bhh1,
    const float* __restrict__ fcW, const float* __restrict__ fcb,
    float* __restrict__ out)
{
  const int b   = blockIdx.x;
  const int tid = threadIdx.x;

  __shared__ alignas(16) half2_t xp[2][I_/2];
  __shared__ alignas(16) half2_t h0p[2][H_/2];
  __shared__ alignas(16) half2_t h1p[2][H_/2];
  __shared__ float h0f[H_], h1f[H_];
  __shared__ float rz0[2*H_], rz1[2*H_];

  const size_t xbase = (size_t)b * T_ * I_;

  if (tid < H_) { h0f[tid] = 0.f; h1f[tid] = 0.f; }
  if (tid < H_/2) {
    half2_t z2; z2[0] = (_Float16)0.f; z2[1] = (_Float16)0.f;
    h0p[0][tid] = z2; h0p[1][tid] = z2;
    h1p[0][tid] = z2; h1p[1][tid] = z2;
  }
  if (tid < I_) ((_Float16*)xp[0])[tid] = (_Float16)x[xbase + tid];
  __syncthreads();

  const bool r0 = (tid < G_);
  const int  g  = r0 ? tid : tid - G_;

  half8_t a0{},a1{},a2{},a3{},a4{},a5{},a6{},a7{},
          a8{},a9{},a10{},a11{},a12{},a13{},a14{},a15{};
  half8_t w0{},w1{},w2{},w3{},w4{},w5{},w6{},w7{},
          w8{},w9{},w10{},w11{},w12{},w13{},w14{},w15{};
  float bi, bh;
  if (r0) {
    const float* p0 = Wih0 + (size_t)g * I_;
    CVT8(a0,p0+ 0); CVT8(a1,p0+ 8); CVT8(a2,p0+16); CVT8(a3,p0+24);
    CVT8(a4,p0+32); CVT8(a5,p0+40); CVT8(a6,p0+48); CVT8(a7,p0+56);
    const float* p1 = Whh0 + (size_t)g * H_;
    CVT8(w0 ,p1+  0); CVT8(w1 ,p1+  8); CVT8(w2 ,p1+ 16); CVT8(w3 ,p1+ 24);
    CVT8(w4 ,p1+ 32); CVT8(w5 ,p1+ 40); CVT8(w6 ,p1+ 48); CVT8(w7 ,p1+ 56);
    CVT8(w8 ,p1+ 64); CVT8(w9 ,p1+ 72); CVT8(w10,p1+ 80); CVT8(w11,p1+ 88);
    CVT8(w12,p1+ 96); CVT8(w13,p1+104); CVT8(w14,p1+112); CVT8(w15,p1+120);
    bi = bih0[g]; bh = bhh0[g];
  } else {
    const float* p0 = Wih1 + (size_t)g * H_;
    CVT8(a0 ,p0+  0); CVT8(a1 ,p0+  8); CVT8(a2 ,p0+ 16); CVT8(a3 ,p0+ 24);
    CVT8(a4 ,p0+ 32); CVT8(a5 ,p0+ 40); CVT8(a6 ,p0+ 48); CVT8(a7 ,p0+ 56);
    CVT8(a8 ,p0+ 64); CVT8(a9 ,p0+ 72); CVT8(a10,p0+ 80); CVT8(a11,p0+ 88);
    CVT8(a12,p0+ 96); CVT8(a13,p0+104); CVT8(a14,p0+112); CVT8(a15,p0+120);
    const float* p1 = Whh1 + (size_t)g * H_;
    CVT8(w0 ,p1+  0); CVT8(w1 ,p1+  8); CVT8(w2 ,p1+ 16); CVT8(w3 ,p1+ 24);
    CVT8(w4 ,p1+ 32); CVT8(w5 ,p1+ 40); CVT8(w6 ,p1+ 48); CVT8(w7 ,p1+ 56);
    CVT8(w8 ,p1+ 64); CVT8(w9 ,p1+ 72); CVT8(w10,p1+ 80); CVT8(w11,p1+ 88);
    CVT8(w12,p1+ 96); CVT8(w13,p1+104); CVT8(w14,p1+112); CVT8(w15,p1+120);
    bi = bih1[g]; bh = bhh1[g];
  }

  float* rzW = r0 ? rz0 : rz1;
  float* hfW = r0 ? h0f : h1f;
  _Float16* hpW0 = (_Float16*)(r0 ? h0p[0] : h1p[0]);
  _Float16* hpW1 = (_Float16*)(r0 ? h0p[1] : h1p[1]);

  for (int p = 0; p <= T_; ++p) {
    float ax = 0.f, ah = 0.f, xnext = 0.f;
    const bool act = r0 ? (p < T_) : (p >= 1);
    if (act) {
      const half8_t* hA = (const half8_t*)h0p[(p & 1) ^ 1];
      float s0=0.f, s1=0.f, s2=0.f, s3=0.f;
      float c0=0.f, c1=0.f, c2=0.f, c3=0.f;
      if (r0) {
        if (g < I_ && p + 1 < T_) xnext = x[xbase + (size_t)(p + 1) * I_ + g];
        const half8_t* xr = (const half8_t*)xp[p & 1];
        D8(s0,s1,s2,s3, a0, xr[0]); D8(s0,s1,s2,s3, a1, xr[1]);
        D8(s0,s1,s2,s3, a2, xr[2]); D8(s0,s1,s2,s3, a3, xr[3]);
        D8(s0,s1,s2,s3, a4, xr[4]); D8(s0,s1,s2,s3, a5, xr[5]);
        D8(s0,s1,s2,s3, a6, xr[6]); D8(s0,s1,s2,s3, a7, xr[7]);
        D8(c0,c1,c2,c3, w0 , hA[ 0]); D8(c0,c1,c2,c3, w1 , hA[ 1]);
        D8(c0,c1,c2,c3, w2 , hA[ 2]); D8(c0,c1,c2,c3, w3 , hA[ 3]);
        D8(c0,c1,c2,c3, w4 , hA[ 4]); D8(c0,c1,c2,c3, w5 , hA[ 5]);
        D8(c0,c1,c2,c3, w6 , hA[ 6]); D8(c0,c1,c2,c3, w7 , hA[ 7]);
        D8(c0,c1,c2,c3, w8 , hA[ 8]); D8(c0,c1,c2,c3, w9 , hA[ 9]);
        D8(c0,c1,c2,c3, w10, hA[10]); D8(c0,c1,c2,c3, w11, hA[11]);
        D8(c0,c1,c2,c3, w12, hA[12]); D8(c0,c1,c2,c3, w13, hA[13]);
        D8(c0,c1,c2,c3, w14, hA[14]); D8(c0,c1,c2,c3, w15, hA[15]);
      } else {
        const half8_t* h1r = (const half8_t*)h1p[(p & 1) ^ 1];
        D8(s0,s1,s2,s3, a0 , hA[ 0]); D8(s0,s1,s2,s3, a1 , hA[ 1]);
        D8(s0,s1,s2,s3, a2 , hA[ 2]); D8(s0,s1,s2,s3, a3 , hA[ 3]);
        D8(s0,s1,s2,s3, a4 , hA[ 4]); D8(s0,s1,s2,s3, a5 , hA[ 5]);
        D8(s0,s1,s2,s3, a6 , hA[ 6]); D8(s0,s1,s2,s3, a7 , hA[ 7]);
        D8(s0,s1,s2,s3, a8 , hA[ 8]); D8(s0,s1,s2,s3, a9 , hA[ 9]);
        D8(s0,s1,s2,s3, a10, hA[10]); D8(s0,s1,s2,s3, a11, hA[11]);
        D8(s0,s1,s2,s3, a12, hA[12]); D8(s0,s1,s2,s3, a13, hA[13]);
        D8(s0,s1,s2,s3, a14, hA[14]); D8(s0,s1,s2,s3, a15, hA[15]);
        D8(c0,c1,c2,c3, w0 , h1r[ 0]); D8(c0,c1,c2,c3, w1 , h1r[ 1]);
        D8(c0,c1,c2,c3, w2 , h1r[ 2]); D8(c0,c1,c2,c3, w3 , h1r[ 3]);
        D8(c0,c1,c2,c3, w4 , h1r[ 4]); D8(c0,c1,c2,c3, w5 , h1r[ 5]);
        D8(c0,c1,c2,c3, w6 , h1r[ 6]); D8(c0,c1,c2,c3, w7 , h1r[ 7]);
        D8(c0,c1,c2,c3, w8 , h1r[ 8]); D8(c0,c1,c2,c3, w9 , h1r[ 9]);
        D8(c0,c1,c2,c3, w10, h1r[10]); D8(c0,c1,c2,c3, w11, h1r[11]);
        D8(c0,c1,c2,c3, w12, h1r[12]); D8(c0,c1,c2,c3, w13, h1r[13]);
        D8(c0,c1,c2,c3, w14, h1r[14]); D8(c0,c1,c2,c3, w15, h1r[15]);
      }
      ax = bi + ((s0 + s1) + (s2 + s3));
      ah = bh + ((c0 + c1) + (c2 + c3));
      if (g < 2*H_) rzW[g] = sigm2_(ax + ah);
    }
    __syncthreads();
    if (act) {
      if (g >= 2*H_) {
        const int jj = g - 2*H_;
        const float r = rzW[jj], z = rzW[H_ + jj];
        const float n = tanh2_(ax + r * ah);
        const float hn = z * (hfW[jj] - n) + n;
        hfW[jj] = hn;
        ((p & 1) ? hpW1 : hpW0)[jj] = (_Float16)hn;
      }
      if (r0 && g < I_ && p + 1 < T_)
        ((_Float16*)xp[(p + 1) & 1])[g] = (_Float16)xnext;
    }
    __syncthreads();
  }

  if (tid < O_) {
    float acc = fcb[tid];
    const float* wr = fcW + (size_t)tid * H_;
    for (int k = 0; k < H_; ++k) acc = fmaf(h1f[k], wr[k], acc);
    out[(size_t)b * O_ + tid] = acc;
  }
}

extern "C" void kernel_launch(void* const* d_in, const int* in_sizes, int n_in,
                              void* d_out, int out_size, void* d_ws, size_t ws_size,
                              hipStream_t stream) {
  const float* x    = (const float*)d_in[0];
  const float* Wih0 = (const float*)d_in[1];
  const float* Whh0 = (const float*)d_in[2];
  const float* bih0 = (const float*)d_in[3];
  const float* bhh0 = (const float*)d_in[4];
  const float* Wih1 = (const float*)d_in[5];
  const float* Whh1 = (const float*)d_in[6];
  const float* bih1 = (const float*)d_in[7];
  const float* bhh1 = (const float*)d_in[8];
  const float* fcW  = (const float*)d_in[9];
  const float* fcb  = (const float*)d_in[10];

  if (ws_size >= WS_NEED) {
    ushort* wsh = (ushort*)d_ws;
    gru_l0<<<dim3(B_), dim3(1024), 0, stream>>>(x, Wih0, Whh0, bih0, bhh0, wsh);
    gru_l1<<<dim3(B_), dim3(1024), 0, stream>>>(wsh, Wih1, Whh1, bih1, bhh1,
                                                fcW, fcb, (float*)d_out);
  } else {
    gru_net<<<dim3(B_), dim3(768), 0, stream>>>(
        x, Wih0, Whh0, bih0, bhh0, Wih1, Whh1, bih1, bhh1, fcW, fcb,
        (float*)d_out);
  }
}

// Round 8
// 2552.656 us; speedup vs baseline: 1.2359x; 1.2359x over previous
//
#include <hip/hip_runtime.h>
#include <hip/hip_bf16.h>

#define B_ 256
#define T_ 2048
#define I_ 64
#define H_ 128
#define G_ 384   // 3*H
#define O_ 10

typedef _Float16 half2_t __attribute__((ext_vector_type(2)));
typedef _Float16 half8_t __attribute__((ext_vector_type(8)));

// Branch-free activations via exp2 (extremes saturate: inf->0/1/±1, no NaN
// for finite inputs).
__device__ __forceinline__ float sigm_(float s) {
  float e = __builtin_amdgcn_exp2f(s * -1.44269504f);
  return __builtin_amdgcn_rcpf(1.f + e);
}
__device__ __forceinline__ float tanh_(float s) {
  float e = __builtin_amdgcn_exp2f(s * 2.88539009f);
  return 1.f - 2.f * __builtin_amdgcn_rcpf(1.f + e);
}

// 8 fp32 -> one named half8 SSA value (4 VGPRs). Named vectors, no arrays:
// R1/R2 showed half2_t wi[64] arrays defeat SROA -> permanent scratch.
#define LOADW(DST, SRC) do { const float* s_ = (SRC); half8_t w_; \
  w_[0]=(_Float16)s_[0]; w_[1]=(_Float16)s_[1]; w_[2]=(_Float16)s_[2]; w_[3]=(_Float16)s_[3]; \
  w_[4]=(_Float16)s_[4]; w_[5]=(_Float16)s_[5]; w_[6]=(_Float16)s_[6]; w_[7]=(_Float16)s_[7]; \
  (DST) = w_; } while(0)

// 4 fdot2 into 4 accumulators; constant even-lane half2 extraction is a pure
// subregister reference (half8 = 4 VGPRs, pair j = VGPR j).
#define D8(S0,S1,S2,S3,W,XV) do { half8_t xv_ = (XV); half8_t w_ = (W); \
  S0 = __builtin_amdgcn_fdot2(__builtin_shufflevector(w_,w_,0,1), __builtin_shufflevector(xv_,xv_,0,1), (S0), false); \
  S1 = __builtin_amdgcn_fdot2(__builtin_shufflevector(w_,w_,2,3), __builtin_shufflevector(xv_,xv_,2,3), (S1), false); \
  S2 = __builtin_amdgcn_fdot2(__builtin_shufflevector(w_,w_,4,5), __builtin_shufflevector(xv_,xv_,4,5), (S2), false); \
  S3 = __builtin_amdgcn_fdot2(__builtin_shufflevector(w_,w_,6,7), __builtin_shufflevector(xv_,xv_,6,7), (S3), false); \
} while(0)

// Convergent barriers (R4/R5 structure, passed twice): one loop, ALL threads,
// __syncthreads() at loop scope only, role divergence strictly between
// barriers. Both roles share the same 32 named half8 weight regs.
//
// LDS PAD (the R7 insight): R1-R6 showed VGPR_Count always = 512/(2*waves per
// SIMD) -- 84 at 768thr, 64 at 1024thr -- because with tiny LDS the backend
// budgets registers for TWO blocks/CU and remats the weight loads every phase
// to fit. Grid=256=#CUs means a 2nd block never exists. Padding LDS to ~105KB
// makes 1 block/CU the declared occupancy too, raising the budget to
// 512/3=170 so the ~128 weight VGPRs stay resident. Zero occupancy cost.
__global__ __launch_bounds__(768)
__attribute__((amdgpu_waves_per_eu(3, 3)))
void gru_net(
    const float* __restrict__ x,
    const float* __restrict__ Wih0, const float* __restrict__ Whh0,
    const float* __restrict__ bih0, const float* __restrict__ bhh0,
    const float* __restrict__ Wih1, const float* __restrict__ Whh1,
    const float* __restrict__ bih1, const float* __restrict__ bhh1,
    const float* __restrict__ fcW, const float* __restrict__ fcb,
    float* __restrict__ out)
{
  const int b   = blockIdx.x;
  const int tid = threadIdx.x;

  __shared__ alignas(16) half2_t xp[2][I_/2];    // x_t fp16, double-buffered
  __shared__ alignas(16) half2_t h0p[2][H_/2];   // h0 fp16, double-buffered
  __shared__ alignas(16) half2_t h1p[2][H_/2];   // h1 fp16, double-buffered
  __shared__ float h0f[H_], h1f[H_];             // fp32 hidden states
  __shared__ float rz0[2*H_], rz1[2*H_];         // r,z gate values
  __shared__ char lds_pad[105 * 1024];           // occupancy pad (see header)
  if ((int)blockIdx.x == -1) lds_pad[tid] = 1;   // unprovable-false: keeps pad

  const size_t xbase = (size_t)b * T_ * I_;

  if (tid < H_) { h0f[tid] = 0.f; h1f[tid] = 0.f; }
  if (tid < H_/2) {
    half2_t z2; z2[0] = (_Float16)0.f; z2[1] = (_Float16)0.f;
    h0p[0][tid] = z2; h0p[1][tid] = z2;
    h1p[0][tid] = z2; h1p[1][tid] = z2;
  }
  if (tid < I_) ((_Float16*)xp[0])[tid] = (_Float16)x[xbase + tid];
  __syncthreads();

  const bool r0 = (tid < G_);            // role: layer-0 vs layer-1 (lag 1)
  const int  g  = r0 ? tid : tid - G_;   // gate index within layer

  // Unified weight registers (32 x half8 = 128 VGPRs, shared by both roles).
  half8_t a0{},a1{},a2{},a3{},a4{},a5{},a6{},a7{},
          a8{},a9{},a10{},a11{},a12{},a13{},a14{},a15{};
  half8_t w0{},w1{},w2{},w3{},w4{},w5{},w6{},w7{},
          w8{},w9{},w10{},w11{},w12{},w13{},w14{},w15{};
  float bi, bh;
  if (r0) {
    const float* p0 = Wih0 + (size_t)g * I_;
    LOADW(a0,p0+ 0); LOADW(a1,p0+ 8); LOADW(a2,p0+16); LOADW(a3,p0+24);
    LOADW(a4,p0+32); LOADW(a5,p0+40); LOADW(a6,p0+48); LOADW(a7,p0+56);
    const float* p1 = Whh0 + (size_t)g * H_;
    LOADW(w0 ,p1+  0); LOADW(w1 ,p1+  8); LOADW(w2 ,p1+ 16); LOADW(w3 ,p1+ 24);
    LOADW(w4 ,p1+ 32); LOADW(w5 ,p1+ 40); LOADW(w6 ,p1+ 48); LOADW(w7 ,p1+ 56);
    LOADW(w8 ,p1+ 64); LOADW(w9 ,p1+ 72); LOADW(w10,p1+ 80); LOADW(w11,p1+ 88);
    LOADW(w12,p1+ 96); LOADW(w13,p1+104); LOADW(w14,p1+112); LOADW(w15,p1+120);
    bi = bih0[g]; bh = bhh0[g];
  } else {
    const float* p0 = Wih1 + (size_t)g * H_;
    LOADW(a0 ,p0+  0); LOADW(a1 ,p0+  8); LOADW(a2 ,p0+ 16); LOADW(a3 ,p0+ 24);
    LOADW(a4 ,p0+ 32); LOADW(a5 ,p0+ 40); LOADW(a6 ,p0+ 48); LOADW(a7 ,p0+ 56);
    LOADW(a8 ,p0+ 64); LOADW(a9 ,p0+ 72); LOADW(a10,p0+ 80); LOADW(a11,p0+ 88);
    LOADW(a12,p0+ 96); LOADW(a13,p0+104); LOADW(a14,p0+112); LOADW(a15,p0+120);
    const float* p1 = Whh1 + (size_t)g * H_;
    LOADW(w0 ,p1+  0); LOADW(w1 ,p1+  8); LOADW(w2 ,p1+ 16); LOADW(w3 ,p1+ 24);
    LOADW(w4 ,p1+ 32); LOADW(w5 ,p1+ 40); LOADW(w6 ,p1+ 48); LOADW(w7 ,p1+ 56);
    LOADW(w8 ,p1+ 64); LOADW(w9 ,p1+ 72); LOADW(w10,p1+ 80); LOADW(w11,p1+ 88);
    LOADW(w12,p1+ 96); LOADW(w13,p1+104); LOADW(w14,p1+112); LOADW(w15,p1+120);
    bi = bih1[g]; bh = bhh1[g];
  }

  float* rzW = r0 ? rz0 : rz1;
  float* hfW = r0 ? h0f : h1f;
  _Float16* hpW0 = (_Float16*)(r0 ? h0p[0] : h1p[0]);
  _Float16* hpW1 = (_Float16*)(r0 ? h0p[1] : h1p[1]);

  for (int p = 0; p <= T_; ++p) {
    float ax = 0.f, ah = 0.f, xnext = 0.f;
    const bool act = r0 ? (p < T_) : (p >= 1);
    if (act) {
      const half8_t* hA = (const half8_t*)h0p[(p & 1) ^ 1];  // h0 prev phase
      float s0=0.f, s1=0.f, s2=0.f, s3=0.f;
      float c0=0.f, c1=0.f, c2=0.f, c3=0.f;
      if (r0) {
        if (g < I_ && p + 1 < T_) xnext = x[xbase + (size_t)(p + 1) * I_ + g];
        const half8_t* xr = (const half8_t*)xp[p & 1];
        D8(s0,s1,s2,s3, a0, xr[0]); D8(s0,s1,s2,s3, a1, xr[1]);
        D8(s0,s1,s2,s3, a2, xr[2]); D8(s0,s1,s2,s3, a3, xr[3]);
        D8(s0,s1,s2,s3, a4, xr[4]); D8(s0,s1,s2,s3, a5, xr[5]);
        D8(s0,s1,s2,s3, a6, xr[6]); D8(s0,s1,s2,s3, a7, xr[7]);
        D8(c0,c1,c2,c3, w0 , hA[ 0]); D8(c0,c1,c2,c3, w1 , hA[ 1]);
        D8(c0,c1,c2,c3, w2 , hA[ 2]); D8(c0,c1,c2,c3, w3 , hA[ 3]);
        D8(c0,c1,c2,c3, w4 , hA[ 4]); D8(c0,c1,c2,c3, w5 , hA[ 5]);
        D8(c0,c1,c2,c3, w6 , hA[ 6]); D8(c0,c1,c2,c3, w7 , hA[ 7]);
        D8(c0,c1,c2,c3, w8 , hA[ 8]); D8(c0,c1,c2,c3, w9 , hA[ 9]);
        D8(c0,c1,c2,c3, w10, hA[10]); D8(c0,c1,c2,c3, w11, hA[11]);
        D8(c0,c1,c2,c3, w12, hA[12]); D8(c0,c1,c2,c3, w13, hA[13]);
        D8(c0,c1,c2,c3, w14, hA[14]); D8(c0,c1,c2,c3, w15, hA[15]);
      } else {
        const half8_t* h1r = (const half8_t*)h1p[(p & 1) ^ 1];  // h1(p-2)
        D8(s0,s1,s2,s3, a0 , hA[ 0]); D8(s0,s1,s2,s3, a1 , hA[ 1]);
        D8(s0,s1,s2,s3, a2 , hA[ 2]); D8(s0,s1,s2,s3, a3 , hA[ 3]);
        D8(s0,s1,s2,s3, a4 , hA[ 4]); D8(s0,s1,s2,s3, a5 , hA[ 5]);
        D8(s0,s1,s2,s3, a6 , hA[ 6]); D8(s0,s1,s2,s3, a7 , hA[ 7]);
        D8(s0,s1,s2,s3, a8 , hA[ 8]); D8(s0,s1,s2,s3, a9 , hA[ 9]);
        D8(s0,s1,s2,s3, a10, hA[10]); D8(s0,s1,s2,s3, a11, hA[11]);
        D8(s0,s1,s2,s3, a12, hA[12]); D8(s0,s1,s2,s3, a13, hA[13]);
        D8(s0,s1,s2,s3, a14, hA[14]); D8(s0,s1,s2,s3, a15, hA[15]);
        D8(c0,c1,c2,c3, w0 , h1r[ 0]); D8(c0,c1,c2,c3, w1 , h1r[ 1]);
        D8(c0,c1,c2,c3, w2 , h1r[ 2]); D8(c0,c1,c2,c3, w3 , h1r[ 3]);
        D8(c0,c1,c2,c3, w4 , h1r[ 4]); D8(c0,c1,c2,c3, w5 , h1r[ 5]);
        D8(c0,c1,c2,c3, w6 , h1r[ 6]); D8(c0,c1,c2,c3, w7 , h1r[ 7]);
        D8(c0,c1,c2,c3, w8 , h1r[ 8]); D8(c0,c1,c2,c3, w9 , h1r[ 9]);
        D8(c0,c1,c2,c3, w10, h1r[10]); D8(c0,c1,c2,c3, w11, h1r[11]);
        D8(c0,c1,c2,c3, w12, h1r[12]); D8(c0,c1,c2,c3, w13, h1r[13]);
        D8(c0,c1,c2,c3, w14, h1r[14]); D8(c0,c1,c2,c3, w15, h1r[15]);
      }
      ax = bi + ((s0 + s1) + (s2 + s3));
      ah = bh + ((c0 + c1) + (c2 + c3));
      if (g < 2*H_) rzW[g] = sigm_(ax + ah);
    }
    __syncthreads();                     // B2 — convergent, all threads
    if (act) {
      if (g >= 2*H_) {
        const int j = g - 2*H_;
        const float r = rzW[j], z = rzW[H_ + j];
        const float n = tanh_(fmaf(r, ah, ax));
        const float hn = fmaf(z, hfW[j] - n, n);   // (1-z)*n + z*h
        hfW[j] = hn;
        ((p & 1) ? hpW1 : hpW0)[j] = (_Float16)hn;
      }
      if (r0 && g < I_ && p + 1 < T_)
        ((_Float16*)xp[(p + 1) & 1])[g] = (_Float16)xnext;
    }
    __syncthreads();                     // B3 — convergent, all threads
  }

  // ---- final FC on h1(T-1) ----
  if (tid < O_) {
    float acc = fcb[tid];
    const float* wr = fcW + (size_t)tid * H_;
    for (int k = 0; k < H_; ++k) acc = fmaf(h1f[k], wr[k], acc);
    out[(size_t)b * O_ + tid] = acc;
  }
}

extern "C" void kernel_launch(void* const* d_in, const int* in_sizes, int n_in,
                              void* d_out, int out_size, void* d_ws, size_t ws_size,
                              hipStream_t stream) {
  const float* x    = (const float*)d_in[0];
  const float* Wih0 = (const float*)d_in[1];
  const float* Whh0 = (const float*)d_in[2];
  const float* bih0 = (const float*)d_in[3];
  const float* bhh0 = (const float*)d_in[4];
  const float* Wih1 = (const float*)d_in[5];
  const float* Whh1 = (const float*)d_in[6];
  const float* bih1 = (const float*)d_in[7];
  const float* bhh1 = (const float*)d_in[8];
  const float* fcW  = (const float*)d_in[9];
  const float* fcb  = (const float*)d_in[10];

  gru_net<<<dim3(B_), dim3(768), 0, stream>>>(
      x, Wih0, Whh0, bih0, bhh0, Wih1, Whh1, bih1, bhh1, fcW, fcb,
      (float*)d_out);
}